// Round 20
// baseline (513.681 us; speedup 1.0000x reference)
//
#include <hip/hip_runtime.h>
#include <stdint.h>

typedef short bf16x8 __attribute__((ext_vector_type(8)));
typedef float f32x4  __attribute__((ext_vector_type(4)));

#define GLOAD_LDS16(gp, lp) \
    __builtin_amdgcn_global_load_lds((const __attribute__((address_space(1))) void*)(gp), \
                                     (__attribute__((address_space(3))) void*)(lp), 16, 0, 0)

__device__ __forceinline__ uint32_t bfbits(float f) {
    uint32_t u = __builtin_bit_cast(uint32_t, f);
    u += 0x7FFFu + ((u >> 16) & 1u);   // round-to-nearest-even
    return u >> 16;
}
__device__ __forceinline__ uint32_t pk2(float a, float b) {
    return bfbits(a) | (bfbits(b) << 16);
}

// Wt[t][c][j][ic] = bf16(W[dy][dx][ic][j*4+c]); quadrant c owns oc = j*4+c.
__global__ void wt_kernel(const float* __restrict__ W, short* __restrict__ Wt) {
    int idx = blockIdx.x * 256 + threadIdx.x;      // 147456
    if (idx < 147456) {
        int t  = idx >> 14;
        int r  = idx & 16383;
        int c  = r >> 12;
        int j  = (r >> 6) & 63;
        int ic = r & 63;
        Wt[idx] = (short)bfbits(W[(t * 64 + ic) * 256 + j * 4 + c]);
    }
}

#define NRING 7
#define ASLOT_B 8448                     // bytes per A h-row slot (66*64*2)
#define B_OFF   (NRING * ASLOT_B)        // 59,136 : B dbuf starts here
#define SMEM_SHORTS ((B_OFF + 2 * 8192) / 2)   // 75,520 B -> 2 blocks/CU

// Implicit-GEMM conv3x3 + bias + pixel_shuffle quadrant, bf16 MFMA.
// r15 structure (B per-tap LDS stream, A-ring 7, two-barrier taps, counted
// vmcnt, double-acc store-spread) + FUSED f32->bf16 A-staging (no prep pass).
// x rows loaded f32->regs at taps 0-1 / 4-5, cvt+ds_written at taps 3 / 7.
// FIXES vs r19: tile 5 is a full steady tile (stages row hbase+24 it reads);
// STGLOAD clamps hy<=191 (no OOB); CVTW zeroes the h>=192 halo.
__global__ __launch_bounds__(256, 2) void conv_ps_kernel(
    const float* __restrict__ x, const short* __restrict__ Wt,
    const float* __restrict__ bias, float* __restrict__ out)
{
    __shared__ short smem[SMEM_SHORTS];

    const int tid   = threadIdx.x;
    const int lane  = tid & 63;
    const int wv    = tid >> 6;       // 0..3 : which h-row of the tile
    const int row_l = lane & 15;
    const int grp   = lane >> 4;
    const int b7    = row_l & 7;

    // XCD-aware bijective swizzle (nwg = 1536 % 8 == 0); c innermost.
    const int raw = blockIdx.x;
    const int lb  = (raw & 7) * 192 + (raw >> 3);
    const int c    = lb & 3;
    const int wt   = (lb >> 2) % 3;
    const int hseg = (lb / 12) % 8;
    const int n    = lb / 96;
    const int w0   = wt * 64;
    const int hbase = hseg * 24;
    const int q = c & 1, p = (c >> 1) & 1;

    const short* wsrc = Wt + c * 4096;             // [t][c][j][ic], t-stride 16384

    auto issueB = [&](int tap, int buf) {          // 2 gload_lds per wave
        #pragma unroll
        for (int r = 0; r < 2; ++r) {
            int cch = tid + r * 256;               // 0..511
            int j = cch >> 3, s = cch & 7, ss = s ^ (j & 7);
            GLOAD_LDS16(wsrc + tap * 16384 + j * 64 + ss * 8,
                        (char*)smem + B_OFF + buf * 8192 + (wv * 64 + r * 256) * 16);
        }
    };

    f32x4 stg[9];                                   // staging regs (36 VGPR peak)

// load chunks J0..J0+NJ-1 of a 2-row pair starting at row BASE (clamped read)
#define STGLOAD(BASE, J0, NJ) { \
    _Pragma("unroll") for (int j_ = (J0); j_ < (J0) + (NJ); ++j_) { \
        int cid_ = tid + j_ * 256; int cc_ = cid_ < 2112 ? cid_ : 0; \
        int rl_ = cc_ / 1056, rem_ = cc_ - rl_ * 1056; \
        int wpos_ = rem_ >> 4, c4_ = rem_ & 15; \
        int hy_ = (BASE) + rl_; \
        int hyc_ = hy_ > 191 ? 191 : hy_; \
        int wg_ = w0 - 1 + wpos_; \
        int wgc_ = wg_ < 0 ? 0 : (wg_ > 191 ? 191 : wg_); \
        stg[j_] = *(const f32x4*)(x + (((size_t)n * 192 + hyc_) * 192 + wgc_) * 64 + c4_ * 4); \
    } }

// convert + ds_write the staged pair (rows BASE,BASE+1); zero h/w halo
#define CVTW(BASE) { \
    _Pragma("unroll") for (int j_ = 0; j_ < 9; ++j_) { \
        int cid_ = tid + j_ * 256; \
        if (cid_ < 2112) { \
            int rl_ = cid_ / 1056, rem_ = cid_ - rl_ * 1056; \
            int wpos_ = rem_ >> 4, c4_ = rem_ & 15; \
            int hy_ = (BASE) + rl_; \
            int wg_ = w0 - 1 + wpos_; \
            uint2 pr_; pr_.x = pk2(stg[j_][0], stg[j_][1]); pr_.y = pk2(stg[j_][2], stg[j_][3]); \
            if ((unsigned)wg_ >= 192u || hy_ > 191) { pr_.x = 0; pr_.y = 0; } \
            int slot_ = (hy_ + 1) % NRING; \
            *(uint2*)&smem[slot_ * 4224 + wpos_ * 64 + \
                           (((c4_ >> 1) ^ (wpos_ & 7)) << 3) + (c4_ & 1) * 4] = pr_; \
        } } }

    // ---- prologue: B(0) -> buf0 ; stage rows hbase-1 .. hbase+3 from f32 x ----
    issueB(0, 0);
    #pragma unroll 3
    for (int k = 0; k < 21; ++k) {
        int cid = tid + k * 256;
        if (cid < 5280) {
            int rl = cid / 1056, rem = cid - rl * 1056;
            int wpos = rem >> 4, c4 = rem & 15;
            int hy = hbase - 1 + rl;
            int wg = w0 - 1 + wpos;
            int hyc = hy < 0 ? 0 : hy;
            int wgc = wg < 0 ? 0 : (wg > 191 ? 191 : wg);
            f32x4 v = *(const f32x4*)(x + (((size_t)n * 192 + hyc) * 192 + wgc) * 64 + c4 * 4);
            uint2 pr; pr.x = pk2(v[0], v[1]); pr.y = pk2(v[2], v[3]);
            if (hy < 0 || (unsigned)wg >= 192u) { pr.x = 0; pr.y = 0; }
            int slot = (hy + 1 + NRING) % NRING;
            *(uint2*)&smem[slot * 4224 + wpos * 64 +
                           (((c4 >> 1) ^ (wpos & 7)) << 3) + (c4 & 1) * 4] = pr;
        }
    }
    asm volatile("s_waitcnt vmcnt(0)" ::: "memory");
    __builtin_amdgcn_sched_barrier(0);
    __syncthreads();

    f32x4 bv4[4];
    #pragma unroll
    for (int nt = 0; nt < 4; ++nt) {
        const int j0 = nt * 16 + grp * 4;
        #pragma unroll
        for (int jv = 0; jv < 4; ++jv)
            bv4[nt][jv] = bias[(j0 + jv) * 4 + c];
    }

    f32x4 accA[4][4], accB[4][4];

#define SCHB __builtin_amdgcn_sched_barrier(0)

#define COMPUTE_TAP(ACC, DY, DX, BUF) { \
    const int rd = row_l + (DX); \
    const int a7 = rd & 7; \
    const int aB = sl[DY] * 4224 + rd * 64; \
    const short* bbase = smem + B_OFF / 2 + (BUF) * 4096 + row_l * 64; \
    _Pragma("unroll") for (int ks = 0; ks < 2; ++ks) { \
        const int kg = ks * 4 + grp; \
        const short* ap = &smem[aB + ((kg ^ a7) << 3)]; \
        const short* bp = bbase + ((kg ^ b7) << 3); \
        bf16x8 af[4], bfr[4]; \
        _Pragma("unroll") for (int mt = 0; mt < 4; ++mt) af[mt]  = *(const bf16x8*)(ap + mt * 1024); \
        _Pragma("unroll") for (int nt = 0; nt < 4; ++nt) bfr[nt] = *(const bf16x8*)(bp + nt * 1024); \
        _Pragma("unroll") for (int mt = 0; mt < 4; ++mt) \
            _Pragma("unroll") for (int nt = 0; nt < 4; ++nt) \
                ACC[mt][nt] = __builtin_amdgcn_mfma_f32_16x16x32_bf16( \
                    bfr[nt], af[mt], ACC[mt][nt], 0, 0, 0); \
    } }

#define ST2(ACCO, S) { \
    const int mt_ = (S) >> 1, n0_ = ((S) & 1) * 2; \
    float* po_ = out + ((rowb_o + 2 * (w0 + mt_ * 16 + row_l) + p) * 64 + grp * 4); \
    __builtin_nontemporal_store(ACCO[mt_][n0_],     (f32x4*)(po_ + n0_ * 16)); \
    __builtin_nontemporal_store(ACCO[mt_][n0_ + 1], (f32x4*)(po_ + (n0_ + 1) * 16)); }

#define TAPX(ACC, K, DY, DX, PAR, VMSTR, EXTRA, STS) \
    __builtin_amdgcn_s_barrier(); SCHB; \
    issueB(((K) + 1) % 9, ((PAR) + (K) + 1) & 1); \
    EXTRA; SCHB; \
    STS; SCHB; \
    asm volatile("s_waitcnt " VMSTR ::: "memory"); SCHB; \
    __builtin_amdgcn_s_barrier(); SCHB; \
    COMPUTE_TAP(ACC, DY, DX, ((PAR) + (K)) & 1)

#define TILE_HEAD(ACC, ITV) \
    const int h0 = hbase + (ITV) * 4; \
    int sl[3]; \
    _Pragma("unroll") for (int dy = 0; dy < 3; ++dy) sl[dy] = (h0 + wv + dy) % NRING; \
    _Pragma("unroll") for (int i = 0; i < 4; ++i) \
        _Pragma("unroll") for (int j = 0; j < 4; ++j) ACC[i][j] = bv4[j];

// steady tile: stages rows h0+4..h0+7 (pairs at taps 0-1/4-5, cvt at 3/7),
// stores ACCO spread 2-chunks/tap. vmcnt counts from per-wave FIFO audit.
#define STEADY_TILE(ACC, ACCO, ITV, PAR) { \
    TILE_HEAD(ACC, ITV); \
    const long rowb_o = ((long)(n * 384 + 2 * (h0 - 4 + wv) + q)) * 384; \
    TAPX(ACC, 0, 0, 0, PAR, "vmcnt(9)",              STGLOAD(h0 + 4, 0, 5), ST2(ACCO, 0)); \
    TAPX(ACC, 1, 0, 1, PAR, "vmcnt(15)",             STGLOAD(h0 + 4, 5, 4), ST2(ACCO, 1)); \
    TAPX(ACC, 2, 0, 2, PAR, "vmcnt(10)",             {}, ST2(ACCO, 2)); \
    TAPX(ACC, 3, 1, 0, PAR, "vmcnt(6) lgkmcnt(0)",   CVTW(h0 + 4), ST2(ACCO, 3)); \
    TAPX(ACC, 4, 1, 1, PAR, "vmcnt(11)",             STGLOAD(h0 + 6, 0, 5), ST2(ACCO, 4)); \
    TAPX(ACC, 5, 1, 2, PAR, "vmcnt(15)",             STGLOAD(h0 + 6, 5, 4), ST2(ACCO, 5)); \
    TAPX(ACC, 6, 2, 0, PAR, "vmcnt(10)",             {}, ST2(ACCO, 6)); \
    TAPX(ACC, 7, 2, 1, PAR, "vmcnt(6) lgkmcnt(0)",   CVTW(h0 + 6), ST2(ACCO, 7)); \
    TAPX(ACC, 8, 2, 2, PAR, "vmcnt(4)",              {}, {}); }

    // ---- tile 0 (peeled: no old stores) ----
    {
        TILE_HEAD(accA, 0);
        TAPX(accA, 0, 0, 0, 0, "vmcnt(7)",            STGLOAD(h0 + 4, 0, 5), {});
        TAPX(accA, 1, 0, 1, 0, "vmcnt(11)",           STGLOAD(h0 + 4, 5, 4), {});
        TAPX(accA, 2, 0, 2, 0, "vmcnt(6)",            {}, {});
        TAPX(accA, 3, 1, 0, 0, "vmcnt(2) lgkmcnt(0)", CVTW(h0 + 4), {});
        TAPX(accA, 4, 1, 1, 0, "vmcnt(7)",            STGLOAD(h0 + 6, 0, 5), {});
        TAPX(accA, 5, 1, 2, 0, "vmcnt(11)",           STGLOAD(h0 + 6, 5, 4), {});
        TAPX(accA, 6, 2, 0, 0, "vmcnt(6)",            {}, {});
        TAPX(accA, 7, 2, 1, 0, "vmcnt(2) lgkmcnt(0)", CVTW(h0 + 6), {});
        TAPX(accA, 8, 2, 2, 0, "vmcnt(2)",            {}, {});
    }
    // ---- tiles 1..4 ----
    #pragma unroll 1
    for (int it2 = 1; it2 < 5; it2 += 2) {
        STEADY_TILE(accB, accA, it2, 1);
        STEADY_TILE(accA, accB, it2 + 1, 0);
    }
    // ---- tile 5: full steady tile (stages row hbase+24 which it reads;
    //      rows >= 192 become zeros via the CVTW h-halo check) ----
    STEADY_TILE(accB, accA, 5, 1);
    // ---- final: store tile 5's acc directly ----
    {
        const int h = hbase + 20 + wv;
        const long rowb = ((long)(n * 384 + 2 * h + q)) * 384;
        #pragma unroll
        for (int mt = 0; mt < 4; ++mt) {
            float* po = out + ((rowb + 2 * (w0 + mt * 16 + row_l) + p) * 64 + grp * 4);
            #pragma unroll
            for (int nt = 0; nt < 4; ++nt)
                __builtin_nontemporal_store(accB[mt][nt], (f32x4*)(po + nt * 16));
        }
    }
#undef STEADY_TILE
#undef TILE_HEAD
#undef TAPX
#undef ST2
#undef COMPUTE_TAP
#undef CVTW
#undef STGLOAD
#undef SCHB
}

extern "C" void kernel_launch(void* const* d_in, const int* in_sizes, int n_in,
                              void* d_out, int out_size, void* d_ws, size_t ws_size,
                              hipStream_t stream) {
    const float* x = (const float*)d_in[0];
    const float* W = (const float*)d_in[1];
    const float* b = (const float*)d_in[2];
    float* out = (float*)d_out;
    short* Wt = (short*)d_ws;   // 294,912 B

    hipLaunchKernelGGL(wt_kernel, dim3(576), dim3(256), 0, stream, W, Wt);
    hipLaunchKernelGGL(conv_ps_kernel, dim3(1536), dim3(256), 0, stream, x, Wt, b, out);
}